// Round 1
// baseline (209.997 us; speedup 1.0000x reference)
//
#include <hip/hip_runtime.h>
#include <cstdint>
#include <cstddef>

// DotProductAttention: O = softmax_q(QK^T/8 + log(mask)) @ V
// P = mask * exp(QK^T/8); L[b,k] = sum_q P; O = P @ (diag(1/L) V).
// R3: (a) materialize P (bf16) in workspace -> PV pass is a pure streaming GEMM
//     (no QK^T/exp/mask recompute); (b) producer is barrier-free: A-fragments
//     loaded directly from global (LDS staging had zero reuse), P transposed
//     reg->global through an 8KB same-wave LDS roundtrip (XOR-swizzled,
//     conflict-free); (c) memsets + 1/8 scale folded into the cast kernel.
// Dispatches: cast -> prod -> vtrans -> pv (4 total).

#define LSEQ 2048
#define DHEAD 64

typedef __bf16 v8bf __attribute__((ext_vector_type(8)));
typedef __bf16 v4bf __attribute__((ext_vector_type(4)));
typedef float v4f __attribute__((ext_vector_type(4)));

#define MFMA16(a, b, c) __builtin_amdgcn_mfma_f32_16x16x32_bf16(a, b, c, 0, 0, 0)

// ---- K0: cast Q (x0.125, exact) and K to bf16; zero out and Lsum ------------
__global__ __launch_bounds__(256) void cast_qk(const float* __restrict__ Q,
                                               const float* __restrict__ K,
                                               __bf16* __restrict__ Qb,
                                               __bf16* __restrict__ Kb,
                                               float* __restrict__ outz,
                                               float* __restrict__ Lz) {
  size_t j = (size_t)blockIdx.x * 256 + threadIdx.x;
  size_t i = j * 4;
  float4 q = *(const float4*)(Q + i);
  float4 k = *(const float4*)(K + i);
  v4bf qo = {(__bf16)(q.x * 0.125f), (__bf16)(q.y * 0.125f),
             (__bf16)(q.z * 0.125f), (__bf16)(q.w * 0.125f)};
  v4bf ko = {(__bf16)k.x, (__bf16)k.y, (__bf16)k.z, (__bf16)k.w};
  *(v4bf*)(Qb + i) = qo;
  *(v4bf*)(Kb + i) = ko;
  float4 z = {0.f, 0.f, 0.f, 0.f};
  *(float4*)(outz + i) = z;  // out is exactly 16*2048*64 = 2M floats = grid*4
  if (j < (size_t)16 * LSEQ) Lz[j] = 0.f;
}

// ---- K1: P[b,q,k] = mask*exp(S), Lsum[b,k] += colsum. BARRIER-FREE ----------
// Grid: bl(bg) x qc(4) x kt(32). XCD = bx%8 = kt%8 -> 2MB mask col-slice / L2.
// Persistent K frags; A frags direct from global (L2/L3); P tile goes through
// an XOR-swizzled LDS roundtrip (same-wave rows only -> no barrier) so global
// stores are 16B/lane, 64B-segment coalesced.
__global__ __launch_bounds__(256) void prod_k(const __bf16* __restrict__ Qb,
                                              const __bf16* __restrict__ Kb,
                                              const float* __restrict__ mask,
                                              float* __restrict__ Lsum,
                                              __bf16* __restrict__ Pg,
                                              int b0) {
  const int bx = blockIdx.x;
  const int bl = bx >> 7;
  const int b = b0 + bl;
  const int qc = (bx >> 5) & 3;
  const int k0 = (bx & 31) * 64;
  const int tid = threadIdx.x;
  const int w = tid >> 6, lane = tid & 63;
  const int quad = lane >> 4, n = lane & 15;

  __shared__ __align__(16) __bf16 Pt[64 * 64];
  __shared__ float psum[4][64];

  // Persistent K fragments: B[d][k'] , lane n holds row k0+sub*16+n
  v8bf bk[4][2];
#pragma unroll
  for (int sub = 0; sub < 4; ++sub)
#pragma unroll
    for (int dh = 0; dh < 2; ++dh)
      bk[sub][dh] = *(const v8bf*)(Kb + ((size_t)b * LSEQ + k0 + sub * 16 + n) * DHEAD +
                                   dh * 32 + quad * 8);

  float colsum[4] = {0.f, 0.f, 0.f, 0.f};
  const int rrow = w * 16 + (lane >> 2);  // readback row (own wave's rows)
  const int c4 = lane & 3;

  const int qbeg = qc * 512, qend = qbeg + 512;
  // prologue A-frag load
  v8bf aq[2];
  {
    const size_t qgr = (size_t)b * LSEQ + qbeg + w * 16 + n;
    aq[0] = *(const v8bf*)(Qb + qgr * DHEAD + quad * 8);
    aq[1] = *(const v8bf*)(Qb + qgr * DHEAD + 32 + quad * 8);
  }
#pragma unroll 1
  for (int q0 = qbeg; q0 < qend; q0 += 64) {
    // prefetch next iteration's A fragments (dummy-safe on last iter)
    const int qn = (q0 + 64 < qend) ? q0 + 64 : qbeg;
    v8bf nq0, nq1;
    {
      const size_t qgr = (size_t)b * LSEQ + qn + w * 16 + n;
      nq0 = *(const v8bf*)(Qb + qgr * DHEAD + quad * 8);
      nq1 = *(const v8bf*)(Qb + qgr * DHEAD + 32 + quad * 8);
    }

#pragma unroll
    for (int sub = 0; sub < 4; ++sub) {
      v4f c = {0.f, 0.f, 0.f, 0.f};
      c = MFMA16(aq[0], bk[sub][0], c);
      c = MFMA16(aq[1], bk[sub][1], c);
      const int kr = sub * 16 + n;
      const int kg = k0 + kr;
#pragma unroll
      for (int r = 0; r < 4; ++r) {
        const int qrow = w * 16 + quad * 4 + r;  // C layout: row=quad*4+r, col=n
        float p = mask[(size_t)(q0 + qrow) * LSEQ + kg] * __expf(c[r]);
        colsum[sub] += p;
        // XOR-swizzled store: chunk' = chunk ^ (row&7); 2-way write conflict (free)
        Pt[qrow * 64 + ((((kr >> 3)) ^ (qrow & 7)) << 3) + (kr & 7)] = (__bf16)p;
      }
    }

    // same-wave readback (conflict-free: rows alternate low/high 64B halves)
#pragma unroll
    for (int p2 = 0; p2 < 2; ++p2) {
      const int phys = c4 + 4 * ((rrow + p2) & 1);
      const int logi = phys ^ (rrow & 7);
      v8bf v = *(const v8bf*)&Pt[rrow * 64 + phys * 8];
      *(v8bf*)(Pg + ((size_t)bl * LSEQ + q0 + rrow) * LSEQ + k0 + logi * 8) = v;
    }

    aq[0] = nq0;
    aq[1] = nq1;
  }

  // colsum: reduce over quads (rows) then waves, one atomic burst per WG
#pragma unroll
  for (int sub = 0; sub < 4; ++sub) {
    float v = colsum[sub];
    v += __shfl_xor(v, 16);
    v += __shfl_xor(v, 32);
    if (quad == 0) psum[w][sub * 16 + n] = v;
  }
  __syncthreads();
  if (tid < 64) {
    float s = psum[0][tid] + psum[1][tid] + psum[2][tid] + psum[3][tid];
    unsafeAtomicAdd(&Lsum[(size_t)b * LSEQ + k0 + tid], s);
  }
}

// ---- K2: Vts[b][v][k] = bf16(V[b][k][v] / L[b][k]) --------------------------
__global__ __launch_bounds__(256) void vtrans_k(const float* __restrict__ V,
                                                const float* __restrict__ Lsum,
                                                __bf16* __restrict__ Vts, int b0) {
  const int b = b0 + (blockIdx.x >> 6);
  const int k0 = (blockIdx.x & 63) * 32;
  const int tid = threadIdx.x;
  __shared__ float tile[32][65];
  __shared__ float invl[32];
  if (tid < 32) invl[tid] = 1.0f / Lsum[(size_t)b * LSEQ + k0 + tid];
#pragma unroll
  for (int t = 0; t < 8; ++t) {
    int flat = t * 256 + tid;
    int k = flat >> 6, v = flat & 63;
    tile[k][v] = V[((size_t)b * LSEQ + k0 + k) * DHEAD + v];
  }
  __syncthreads();
#pragma unroll
  for (int t = 0; t < 8; ++t) {
    int flat = t * 256 + tid;
    int v = flat >> 5, k = flat & 31;
    Vts[((size_t)b * DHEAD + v) * LSEQ + k0 + k] = (__bf16)(tile[k][v] * invl[k]);
  }
}

// ---- K3: O = P @ Vts — pure streaming GEMM, no LDS, no barriers -------------
// Grid: qt(32) x kc(2) x bl(bg). XCD = bl%8 -> 2 batches/XCD (Vts slab 512KB in L2).
// Per wave: 16 q-rows x 64 v, K-half = 1024. A frags stream P from HBM/L3
// (64B-coalesced), B frags hit L1/L2. kc-split doubles occupancy (16 waves/CU).
__global__ __launch_bounds__(256) void pv_k(const __bf16* __restrict__ Pg,
                                            const __bf16* __restrict__ Vts,
                                            float* __restrict__ out,
                                            int b0, int bgm, int bgs) {
  const int bx = blockIdx.x;
  const int bl = bx & bgm;
  const int rest = bx >> bgs;
  const int kc = rest & 1;
  const int qt = rest >> 1;
  const int b = b0 + bl;
  const int q0 = qt * 64;
  const int tid = threadIdx.x;
  const int w = tid >> 6, lane = tid & 63;
  const int quad = lane >> 4, n = lane & 15;

  const __bf16* pbase =
      Pg + ((size_t)bl * LSEQ + q0 + w * 16 + n) * LSEQ + kc * 1024 + quad * 8;
  const __bf16* vbase = Vts + ((size_t)b * DHEAD + n) * LSEQ + kc * 1024 + quad * 8;

  v4f acc[4];
#pragma unroll
  for (int vs = 0; vs < 4; ++vs) acc[vs] = (v4f){0.f, 0.f, 0.f, 0.f};

#pragma unroll 4
  for (int i = 0; i < 32; ++i) {
    v8bf ap = *(const v8bf*)(pbase + i * 32);
#pragma unroll
    for (int vs = 0; vs < 4; ++vs) {
      v8bf bv = *(const v8bf*)(vbase + (size_t)vs * 16 * LSEQ + i * 32);
      acc[vs] = MFMA16(ap, bv, acc[vs]);
    }
  }

#pragma unroll
  for (int vs = 0; vs < 4; ++vs)
#pragma unroll
    for (int r = 0; r < 4; ++r)
      unsafeAtomicAdd(
          &out[((size_t)b * LSEQ + q0 + w * 16 + quad * 4 + r) * DHEAD + vs * 16 + n],
          acc[vs][r]);
}

extern "C" void kernel_launch(void* const* d_in, const int* in_sizes, int n_in,
                              void* d_out, int out_size, void* d_ws, size_t ws_size,
                              hipStream_t stream) {
  const float* Q = (const float*)d_in[0];
  const float* K = (const float*)d_in[1];
  const float* V = (const float*)d_in[2];
  const float* mask = (const float*)d_in[3];
  float* out = (float*)d_out;

  char* ws = (char*)d_ws;
  // ws: Qb 4MiB | Kb 4MiB | Vts 4MiB | Lsum 128KiB | P  (bg * 8MiB)
  __bf16* Qb = (__bf16*)(ws);
  __bf16* Kb = (__bf16*)(ws + (4 << 20));
  __bf16* Vts = (__bf16*)(ws + (8 << 20));
  float* Lsum = (float*)(ws + (12 << 20));
  __bf16* Pg = (__bf16*)(ws + (12 << 20) + (1 << 17));
  const size_t base = ((size_t)12 << 20) + (1 << 17);
  const size_t perb = (size_t)LSEQ * LSEQ * 2;  // 8 MiB per batch of P
  if (ws_size < base + perb) return;  // workspace too small — fail loudly

  int bg = (int)((ws_size - base) / perb);
  if (bg > 16) bg = 16;
  while (bg & (bg - 1)) bg &= bg - 1;  // round down to power of two
  int bgs = 0;
  while ((1 << (bgs + 1)) <= bg) ++bgs;

  cast_qk<<<2048, 256, 0, stream>>>(Q, K, Qb, Kb, out, Lsum);
  for (int g = 0; g < 16; g += bg) {
    prod_k<<<bg * 128, 256, 0, stream>>>(Qb, Kb, mask, Lsum, Pg, g);
    vtrans_k<<<bg * 64, 256, 0, stream>>>(V, Lsum, Vts, g);
    pv_k<<<bg * 64, 256, 0, stream>>>(Pg, Vts, out, g, bg - 1, bgs);
  }
}